// Round 1
// baseline (1356.474 us; speedup 1.0000x reference)
//
#include <hip/hip_runtime.h>
#include <cstddef>
#include <cstdint>

#define N_BATCH 32
#define WIDTH   512
#define T_DIM   2048
#define NB_CODE 1024
#define M_ROWS  (N_BATCH * T_DIM)          // 65536
#define OUT_ELEMS (N_BATCH * WIDTH * T_DIM) // 33554432
#define IDX_OFF  OUT_ELEMS
#define LOSS_OFF (OUT_ELEMS + M_ROWS)
#define PERP_OFF (LOSS_OFF + 1)

// ---------------- workspace layout (float units) ----------------
// cbT      : [0,       524288)   codebook transposed [512][1024]
// cnorm    : [524288,  525312)   per-code squared norm
// idx (int): [525312,  590848)   argmin index per row
// hist(int): [590848,  591872)   code histogram
// lossPart : [591872,  592896)   per-block commit-loss partials

// Transpose codebook [1024][512] -> cbT [512][1024]
__global__ void k_transpose_cb(const float* __restrict__ cb, float* __restrict__ cbT) {
    __shared__ float tile[32][33];
    const int c0 = blockIdx.x * 32;
    const int k0 = blockIdx.y * 32;
    const int tx = threadIdx.x, ty = threadIdx.y;
#pragma unroll
    for (int j = 0; j < 32; j += 8)
        tile[ty + j][tx] = cb[(size_t)(c0 + ty + j) * WIDTH + k0 + tx];
    __syncthreads();
#pragma unroll
    for (int j = 0; j < 32; j += 8)
        cbT[(size_t)(k0 + ty + j) * NB_CODE + c0 + tx] = tile[tx][ty + j];
}

// Per-code squared norms
__global__ void k_cnorm(const float* __restrict__ cb, float* __restrict__ cnorm) {
    const int c = blockIdx.x;
    const int lane = threadIdx.x;
    const float4* p = (const float4*)(cb + (size_t)c * WIDTH);
    float s = 0.f;
#pragma unroll
    for (int i = 0; i < 2; ++i) {
        float4 v = p[lane + i * 64];
        s += v.x * v.x + v.y * v.y + v.z * v.z + v.w * v.w;
    }
#pragma unroll
    for (int off = 32; off >= 1; off >>= 1) s += __shfl_xor(s, off, 64);
    if (lane == 0) cnorm[c] = s;
}

// Main distance-matmul + argmin.
// Block: 256 threads, BM=64 rows, BN=128 codes/chunk, BK=64.
// Thread tile: 4 rows x 8 codes. Score = cnorm[c] - 2*dot (argmin-invariant).
__global__ __launch_bounds__(256, 3) void k_argmin(
    const float* __restrict__ x, const float* __restrict__ cbT,
    const float* __restrict__ cnorm, int* __restrict__ idx) {
    __shared__ float xs[64][64];     // [k][row] 16KB
    __shared__ float cs[64][128];    // [k][code] 32KB
    __shared__ float sbest[4][64];
    __shared__ int   sidx[4][64];

    const int tid = threadIdx.x;
    const int tr = tid & 15;   // row group (rows tr*4 .. tr*4+3)
    const int tc = tid >> 4;   // code group (codes tc*8 .. tc*8+7)
    const int m0 = blockIdx.x * 64;
    const int n  = m0 >> 11;           // T_DIM = 2048
    const int t0 = m0 & 2047;
    const float* xblk = x + (size_t)n * WIDTH * T_DIM + t0; // xblk[w*T_DIM + t]

    float best[4]; int bidx[4];
#pragma unroll
    for (int r = 0; r < 4; ++r) { best[r] = 3.4e38f; bidx[r] = 0; }

    for (int cc = 0; cc < NB_CODE; cc += 128) {
        float acc[4][8];
#pragma unroll
        for (int r = 0; r < 4; ++r)
#pragma unroll
            for (int j = 0; j < 8; ++j) acc[r][j] = 0.f;

        for (int kc = 0; kc < WIDTH; kc += 64) {
            // stage x tile: xs[k][row], global is already [w][t] so b128 both sides
            {
                const int i = tid & 15, kk = tid >> 4;
#pragma unroll
                for (int s4 = 0; s4 < 4; ++s4) {
                    const int k = s4 * 16 + kk;
                    float4 v = *(const float4*)(xblk + (size_t)(kc + k) * T_DIM + i * 4);
                    *(float4*)(&xs[k][i * 4]) = v;
                }
            }
            // stage codebook tile from pre-transposed cbT: cs[k][code]
            {
                const int i = tid & 31, kk = tid >> 5;
#pragma unroll
                for (int s8 = 0; s8 < 8; ++s8) {
                    const int k = s8 * 8 + kk;
                    float4 v = *(const float4*)(cbT + (size_t)(kc + k) * NB_CODE + cc + i * 4);
                    *(float4*)(&cs[k][i * 4]) = v;
                }
            }
            __syncthreads();
#pragma unroll 16
            for (int k = 0; k < 64; ++k) {
                float4 xv = *(const float4*)(&xs[k][tr * 4]);
                float4 ca = *(const float4*)(&cs[k][tc * 8]);
                float4 cb4 = *(const float4*)(&cs[k][tc * 8 + 4]);
                const float xr[4] = {xv.x, xv.y, xv.z, xv.w};
                const float cj[8] = {ca.x, ca.y, ca.z, ca.w, cb4.x, cb4.y, cb4.z, cb4.w};
#pragma unroll
                for (int r = 0; r < 4; ++r)
#pragma unroll
                    for (int j = 0; j < 8; ++j)
                        acc[r][j] = fmaf(xr[r], cj[j], acc[r][j]);
            }
            __syncthreads();
        }
        // score + running argmin (earliest index wins ties: ascending scan, strict <)
#pragma unroll
        for (int j = 0; j < 8; ++j) {
            const int c = cc + tc * 8 + j;
            const float cn = cnorm[c];
#pragma unroll
            for (int r = 0; r < 4; ++r) {
                float s = fmaf(-2.f, acc[r][j], cn);
                if (s < best[r]) { best[r] = s; bidx[r] = c; }
            }
        }
    }
    // merge across the 4 tc-groups within the wave (lanes differ in bits 4..5)
#pragma unroll
    for (int off = 16; off <= 32; off <<= 1) {
#pragma unroll
        for (int r = 0; r < 4; ++r) {
            float ob = __shfl_xor(best[r], off, 64);
            int   oi = __shfl_xor(bidx[r], off, 64);
            if (ob < best[r] || (ob == best[r] && oi < bidx[r])) { best[r] = ob; bidx[r] = oi; }
        }
    }
    const int wave = tid >> 6, lane = tid & 63;
    if ((lane >> 4) == 0) {  // one representative per tr group
#pragma unroll
        for (int r = 0; r < 4; ++r) {
            sbest[wave][lane * 4 + r] = best[r];
            sidx[wave][lane * 4 + r]  = bidx[r];
        }
    }
    __syncthreads();
    if (tid < 64) {
        float b = sbest[0][tid]; int bi = sidx[0][tid];
#pragma unroll
        for (int w = 1; w < 4; ++w) {
            float ob = sbest[w][tid]; int oi = sidx[w][tid];
            if (ob < b || (ob == b && oi < bi)) { b = ob; bi = oi; }
        }
        idx[m0 + tid] = bi;
    }
}

// Gather codebook[idx] -> out [N][W][T], write code_idx as float,
// per-block commit-loss partial, histogram atomics.
__global__ __launch_bounds__(256) void k_scatter(
    const float* __restrict__ x, const float* __restrict__ cb,
    const int* __restrict__ idx, float* __restrict__ dout,
    float* __restrict__ lossPart, int* __restrict__ hist) {
    __shared__ int sidx[64];
    __shared__ float swsum[4];
    const int tid = threadIdx.x;
    const int b  = blockIdx.x;
    const int n  = b >> 5;
    const int t0 = (b & 31) * 64;
    if (tid < 64) {
        const int m = n * T_DIM + t0 + tid;
        const int ii = idx[m];
        sidx[tid] = ii;
        dout[IDX_OFF + m] = (float)ii;
        atomicAdd(&hist[ii], 1);
    }
    __syncthreads();
    const int i  = tid & 63;   // t offset (coalesced store dim)
    const int wq = tid >> 6;   // w phase
    const int ii = sidx[i];
    float ls = 0.f;
    for (int w = wq; w < WIDTH; w += 4) {
        const float val = cb[(size_t)ii * WIDTH + w];
        const size_t o = ((size_t)n * WIDTH + w) * T_DIM + t0 + i;
        dout[o] = val;
        const float d = x[o] - val;
        ls = fmaf(d, d, ls);
    }
#pragma unroll
    for (int off = 32; off >= 1; off >>= 1) ls += __shfl_xor(ls, off, 64);
    if ((tid & 63) == 0) swsum[tid >> 6] = ls;
    __syncthreads();
    if (tid == 0) lossPart[b] = swsum[0] + swsum[1] + swsum[2] + swsum[3];
}

// Entropy/perplexity + final commit loss
__global__ __launch_bounds__(256) void k_finalize(
    const int* __restrict__ hist, const float* __restrict__ lossPart,
    float* __restrict__ dout) {
    const int tid = threadIdx.x;
    float e = 0.f, ls = 0.f;
    for (int c = tid; c < NB_CODE; c += 256) {
        const float p = (float)hist[c] * (1.0f / (float)M_ROWS);
        e += p * logf(p + 1e-7f);
        ls += lossPart[c];
    }
#pragma unroll
    for (int off = 32; off >= 1; off >>= 1) {
        e  += __shfl_xor(e, off, 64);
        ls += __shfl_xor(ls, off, 64);
    }
    __shared__ float se[4], sl[4];
    if ((tid & 63) == 0) { se[tid >> 6] = e; sl[tid >> 6] = ls; }
    __syncthreads();
    if (tid == 0) {
        const float E = se[0] + se[1] + se[2] + se[3];
        const float L = sl[0] + sl[1] + sl[2] + sl[3];
        dout[LOSS_OFF] = L / (float)OUT_ELEMS;
        dout[PERP_OFF] = expf(-E);
    }
}

extern "C" void kernel_launch(void* const* d_in, const int* in_sizes, int n_in,
                              void* d_out, int out_size, void* d_ws, size_t ws_size,
                              hipStream_t stream) {
    const float* x  = (const float*)d_in[0];
    const float* cb = (const float*)d_in[1];
    float* dout = (float*)d_out;
    float* ws   = (float*)d_ws;

    float* cbT      = ws;
    float* cnorm    = ws + 524288;
    int*   idx      = (int*)(ws + 525312);
    int*   hist     = (int*)(ws + 590848);
    float* lossPart = ws + 591872;

    hipMemsetAsync(hist, 0, NB_CODE * sizeof(int), stream);

    k_transpose_cb<<<dim3(32, 16), dim3(32, 8), 0, stream>>>(cb, cbT);
    k_cnorm<<<NB_CODE, 64, 0, stream>>>(cb, cnorm);
    k_argmin<<<M_ROWS / 64, 256, 0, stream>>>(x, cbT, cnorm, idx);
    k_scatter<<<1024, 256, 0, stream>>>(x, cb, idx, dout, lossPart, hist);
    k_finalize<<<1, 256, 0, stream>>>(hist, lossPart, dout);
}

// Round 2
// 611.069 us; speedup vs baseline: 2.2198x; 2.2198x over previous
//
#include <hip/hip_runtime.h>
#include <cstddef>
#include <cstdint>

#define N_BATCH 32
#define WIDTH   512
#define T_DIM   2048
#define NB_CODE 1024
#define M_ROWS  (N_BATCH * T_DIM)           // 65536
#define OUT_ELEMS (N_BATCH * WIDTH * T_DIM) // 33554432
#define IDX_OFF  OUT_ELEMS
#define LOSS_OFF (OUT_ELEMS + M_ROWS)
#define PERP_OFF (LOSS_OFF + 1)

typedef __attribute__((ext_vector_type(8))) short vshort8;
typedef __attribute__((ext_vector_type(4))) float vfloat4;

// ---------------- workspace layout (bytes) ----------------
// cbh       : [0, 1MB)          codebook hi-split bf16 [1024][512]
// cbl       : [1MB, 2MB)        codebook lo-split bf16 [1024][512]
// cnorm     : [2MB, 2MB+4KB)    per-code squared norm (fp32)
// cand      : [2MB+4KB, +256KB) packed (i1 | i2<<16) per row
// idx_final : reuse cbh region (written after argmin done with cbh)
// hist      : reuse cbl region
// lossPart  : reuse cbl+4KB

static __device__ __forceinline__ unsigned short f2bf(float f) {
    uint32_t u = __float_as_uint(f);
    uint32_t r = (u + 0x7FFFu + ((u >> 16) & 1u)) >> 16;  // RNE
    return (unsigned short)r;
}
static __device__ __forceinline__ float bf2f(unsigned short s) {
    return __uint_as_float(((uint32_t)s) << 16);
}

// Split codebook into bf16 hi/lo
__global__ __launch_bounds__(256) void k_split(const float* __restrict__ cb,
                                               unsigned short* __restrict__ h,
                                               unsigned short* __restrict__ l) {
    const int i = blockIdx.x * 256 + threadIdx.x;  // 131072 float4s
    float4 v = ((const float4*)cb)[i];
    ushort4 hh, ll;
    hh.x = f2bf(v.x); ll.x = f2bf(v.x - bf2f(hh.x));
    hh.y = f2bf(v.y); ll.y = f2bf(v.y - bf2f(hh.y));
    hh.z = f2bf(v.z); ll.z = f2bf(v.z - bf2f(hh.z));
    hh.w = f2bf(v.w); ll.w = f2bf(v.w - bf2f(hh.w));
    ((ushort4*)h)[i] = hh;
    ((ushort4*)l)[i] = ll;
}

// Per-code squared norms (fp32, from original codebook)
__global__ void k_cnorm(const float* __restrict__ cb, float* __restrict__ cnorm) {
    const int c = blockIdx.x;
    const int lane = threadIdx.x;
    const float4* p = (const float4*)(cb + (size_t)c * WIDTH);
    float s = 0.f;
#pragma unroll
    for (int i = 0; i < 2; ++i) {
        float4 v = p[lane + i * 64];
        s += v.x * v.x + v.y * v.y + v.z * v.z + v.w * v.w;
    }
#pragma unroll
    for (int off = 32; off >= 1; off >>= 1) s += __shfl_xor(s, off, 64);
    if (lane == 0) cnorm[c] = s;
}

// MFMA split-bf16 distance GEMM + top-2 argmin.
// Block: 512 threads = 8 waves; 128 rows/block (16 rows/wave, one N-frag).
// x fragments (full K, h+l) in registers; codebook tiles staged in LDS.
__global__ __launch_bounds__(512, 2) void k_argmin(
    const float* __restrict__ x, const unsigned short* __restrict__ cbh,
    const unsigned short* __restrict__ cbl, const float* __restrict__ cnorm,
    uint32_t* __restrict__ cand) {
    __shared__ __align__(16) unsigned short ldsA[2][2][128 * 72];  // [buf][h/l][code][k+pad]
    __shared__ __align__(16) float cns[NB_CODE];

    const int tid = threadIdx.x;
    const int w = tid >> 6, l = tid & 63;
    const int l15 = l & 15, lg = l >> 4;

    for (int i = tid; i < NB_CODE; i += 512) cns[i] = cnorm[i];

    // ---- x fragment preload: 16 rows/wave, full K=512, split to bf16 h/l ----
    const int m0w = blockIdx.x * 128 + w * 16;
    const int n = m0w >> 11;
    const int t = (m0w & 2047) + l15;
    const float* xb = x + ((size_t)n * WIDTH) * T_DIM + t;
    vshort8 xh[16], xl[16];
#pragma unroll
    for (int ks = 0; ks < 16; ++ks) {
        const int kb = ks * 32 + lg * 8;
#pragma unroll
        for (int e = 0; e < 8; ++e) {
            float v = xb[(size_t)(kb + e) * T_DIM];
            unsigned short hb = f2bf(v);
            float r = v - bf2f(hb);
            unsigned short lb = f2bf(r);
            xh[ks][e] = (short)hb;
            xl[ks][e] = (short)lb;
        }
    }

    // staging slots for this thread
    const int srow0 = tid >> 3;            // rows 0..63
    const int srow1 = (512 + tid) >> 3;    // rows 64..127
    const int scol = (tid & 7) * 8;

    // prefetch tile (cc=0, kc=0)
    int4 pfh[2], pfl[2];
    pfh[0] = *(const int4*)(cbh + (size_t)srow0 * 512 + scol);
    pfl[0] = *(const int4*)(cbl + (size_t)srow0 * 512 + scol);
    pfh[1] = *(const int4*)(cbh + (size_t)srow1 * 512 + scol);
    pfl[1] = *(const int4*)(cbl + (size_t)srow1 * 512 + scol);

    const int lbase = l15 * 72 + lg * 8;
    float b1 = 3.4e38f, b2 = 3.4e38f;
    int i1 = 0, i2 = 0;

    for (int cc = 0; cc < 8; ++cc) {
        vfloat4 acc[8];
#pragma unroll
        for (int fm = 0; fm < 8; ++fm) {
            vfloat4 z = {0.f, 0.f, 0.f, 0.f};
            acc[fm] = z;
        }

#pragma unroll
        for (int kc = 0; kc < 8; ++kc) {
            const int buf = kc & 1;
            __syncthreads();  // everyone done reading buf (2 tiles ago)
            *(int4*)&ldsA[buf][0][srow0 * 72 + scol] = pfh[0];
            *(int4*)&ldsA[buf][0][srow1 * 72 + scol] = pfh[1];
            *(int4*)&ldsA[buf][1][srow0 * 72 + scol] = pfl[0];
            *(int4*)&ldsA[buf][1][srow1 * 72 + scol] = pfl[1];
            __syncthreads();
            // issue prefetch of next tile (lands during MFMA phase)
            const int tt1 = cc * 8 + kc + 1;
            if (tt1 < 64) {
                const int cc1 = tt1 >> 3, kc1 = tt1 & 7;
                const unsigned short* gh = cbh + (size_t)cc1 * 128 * 512 + kc1 * 64;
                const unsigned short* gl = cbl + (size_t)cc1 * 128 * 512 + kc1 * 64;
                pfh[0] = *(const int4*)(gh + (size_t)srow0 * 512 + scol);
                pfl[0] = *(const int4*)(gl + (size_t)srow0 * 512 + scol);
                pfh[1] = *(const int4*)(gh + (size_t)srow1 * 512 + scol);
                pfl[1] = *(const int4*)(gl + (size_t)srow1 * 512 + scol);
            }
#pragma unroll
            for (int ks2 = 0; ks2 < 2; ++ks2) {
                const int kstep = kc * 2 + ks2;
#pragma unroll
                for (int fm = 0; fm < 8; ++fm) {
                    const int off = fm * 1152 + ks2 * 32 + lbase;
                    vshort8 ah = *(const vshort8*)&ldsA[buf][0][off];
                    vshort8 al = *(const vshort8*)&ldsA[buf][1][off];
                    acc[fm] = __builtin_amdgcn_mfma_f32_16x16x32_bf16(ah, xh[kstep], acc[fm], 0, 0, 0);
                    acc[fm] = __builtin_amdgcn_mfma_f32_16x16x32_bf16(ah, xl[kstep], acc[fm], 0, 0, 0);
                    acc[fm] = __builtin_amdgcn_mfma_f32_16x16x32_bf16(al, xh[kstep], acc[fm], 0, 0, 0);
                }
            }
        }
        // ---- score + top-2 update; lane holds codes cb0..cb0+3, row = l15 ----
#pragma unroll
        for (int fm = 0; fm < 8; ++fm) {
            const int cb0 = cc * 128 + fm * 16 + lg * 4;
            vfloat4 cn = *(const vfloat4*)&cns[cb0];
#pragma unroll
            for (int r = 0; r < 4; ++r) {
                const float s = fmaf(-2.f, acc[fm][r], cn[r]);
                const int c = cb0 + r;
                if (s < b1) { b2 = b1; i2 = i1; b1 = s; i1 = c; }
                else if (s < b2) { b2 = s; i2 = c; }
            }
        }
    }
    // merge top-2 across the 4 lane-groups (disjoint code subsets)
#pragma unroll
    for (int off = 16; off <= 32; off <<= 1) {
        float ob1 = __shfl_xor(b1, off, 64); int oi1 = __shfl_xor(i1, off, 64);
        float ob2 = __shfl_xor(b2, off, 64); int oi2 = __shfl_xor(i2, off, 64);
        if (ob1 < b1) {
            float nb2; int ni2;
            if (b1 < ob2) { nb2 = b1; ni2 = i1; } else { nb2 = ob2; ni2 = oi2; }
            b1 = ob1; i1 = oi1; b2 = nb2; i2 = ni2;
        } else {
            if (ob1 < b2) { b2 = ob1; i2 = oi1; }
        }
    }
    if (l < 16) {
        // flag rows needing exact rescore (approx gap below safety threshold)
        uint32_t sec = (b2 - b1 < 0.05f) ? (uint32_t)i2 : 0xFFFFu;
        cand[m0w + l] = (uint32_t)i1 | (sec << 16);
    }
}

// Exact fp32 rescore of flagged rows (top-2 candidates); writes final idx.
__global__ __launch_bounds__(256) void k_rescore(
    const float* __restrict__ x, const float* __restrict__ cb,
    const float* __restrict__ cnorm, const uint32_t* __restrict__ cand,
    int* __restrict__ idx_final) {
    __shared__ float pd[2][4][64];
    const int tid = threadIdx.x;
    const int b = blockIdx.x;
    const int n = b >> 5, t0 = (b & 31) * 64;
    const int tl = tid & 63, kq = tid >> 6;
    const int row = n * T_DIM + t0 + tl;
    const uint32_t pk = cand[row];
    const int ii1 = (int)(pk & 0xFFFFu);
    const uint32_t sec = pk >> 16;
    float d1 = 0.f, d2 = 0.f;
    if (sec != 0xFFFFu) {
        const float* xc = x + (size_t)n * WIDTH * T_DIM + t0 + tl;
        const float* c1 = cb + (size_t)ii1 * WIDTH;
        const float* c2 = cb + (size_t)sec * WIDTH;
#pragma unroll 4
        for (int k = kq * 128; k < kq * 128 + 128; ++k) {
            const float v = xc[(size_t)k * T_DIM];
            d1 = fmaf(v, c1[k], d1);
            d2 = fmaf(v, c2[k], d2);
        }
    }
    pd[0][kq][tl] = d1;
    pd[1][kq][tl] = d2;
    __syncthreads();
    if (tid < 64) {
        const uint32_t pk2 = cand[row];
        const int j1 = (int)(pk2 & 0xFFFFu);
        const uint32_t s2 = pk2 >> 16;
        int win = j1;
        if (s2 != 0xFFFFu) {
            float dd1 = pd[0][0][tid] + pd[0][1][tid] + pd[0][2][tid] + pd[0][3][tid];
            float dd2 = pd[1][0][tid] + pd[1][1][tid] + pd[1][2][tid] + pd[1][3][tid];
            float q1 = fmaf(-2.f, dd1, cnorm[j1]);
            float q2 = fmaf(-2.f, dd2, cnorm[(int)s2]);
            if (q2 < q1 || (q2 == q1 && (int)s2 < j1)) win = (int)s2;
        }
        idx_final[row] = win;
    }
}

// Gather codebook[idx] -> out [N][W][T], write code_idx as float,
// per-block commit-loss partial, histogram atomics.
__global__ __launch_bounds__(256) void k_scatter(
    const float* __restrict__ x, const float* __restrict__ cb,
    const int* __restrict__ idx, float* __restrict__ dout,
    float* __restrict__ lossPart, int* __restrict__ hist) {
    __shared__ int sidx[64];
    __shared__ float swsum[4];
    const int tid = threadIdx.x;
    const int b = blockIdx.x;
    const int n = b >> 5;
    const int t0 = (b & 31) * 64;
    if (tid < 64) {
        const int m = n * T_DIM + t0 + tid;
        const int ii = idx[m];
        sidx[tid] = ii;
        dout[IDX_OFF + m] = (float)ii;
        atomicAdd(&hist[ii], 1);
    }
    __syncthreads();
    const int i = tid & 63;
    const int wq = tid >> 6;
    const int ii = sidx[i];
    float ls = 0.f;
    for (int ww = wq; ww < WIDTH; ww += 4) {
        const float val = cb[(size_t)ii * WIDTH + ww];
        const size_t o = ((size_t)n * WIDTH + ww) * T_DIM + t0 + i;
        dout[o] = val;
        const float d = x[o] - val;
        ls = fmaf(d, d, ls);
    }
#pragma unroll
    for (int off = 32; off >= 1; off >>= 1) ls += __shfl_xor(ls, off, 64);
    if ((tid & 63) == 0) swsum[tid >> 6] = ls;
    __syncthreads();
    if (tid == 0) lossPart[b] = swsum[0] + swsum[1] + swsum[2] + swsum[3];
}

// Entropy/perplexity + final commit loss
__global__ __launch_bounds__(256) void k_finalize(
    const int* __restrict__ hist, const float* __restrict__ lossPart,
    float* __restrict__ dout) {
    const int tid = threadIdx.x;
    float e = 0.f, ls = 0.f;
    for (int c = tid; c < NB_CODE; c += 256) {
        const float p = (float)hist[c] * (1.0f / (float)M_ROWS);
        e += p * logf(p + 1e-7f);
        ls += lossPart[c];
    }
#pragma unroll
    for (int off = 32; off >= 1; off >>= 1) {
        e += __shfl_xor(e, off, 64);
        ls += __shfl_xor(ls, off, 64);
    }
    __shared__ float se[4], sl[4];
    if ((tid & 63) == 0) { se[tid >> 6] = e; sl[tid >> 6] = ls; }
    __syncthreads();
    if (tid == 0) {
        const float E = se[0] + se[1] + se[2] + se[3];
        const float L = sl[0] + sl[1] + sl[2] + sl[3];
        dout[LOSS_OFF] = L / (float)OUT_ELEMS;
        dout[PERP_OFF] = expf(-E);
    }
}

extern "C" void kernel_launch(void* const* d_in, const int* in_sizes, int n_in,
                              void* d_out, int out_size, void* d_ws, size_t ws_size,
                              hipStream_t stream) {
    const float* x = (const float*)d_in[0];
    const float* cb = (const float*)d_in[1];
    float* dout = (float*)d_out;
    uint8_t* w = (uint8_t*)d_ws;

    unsigned short* cbh = (unsigned short*)w;                    // 1 MB
    unsigned short* cbl = (unsigned short*)(w + (1u << 20));     // 1 MB
    float* cnorm = (float*)(w + (2u << 20));                     // 4 KB
    uint32_t* cand = (uint32_t*)(w + (2u << 20) + 4096);         // 256 KB
    int* idx_final = (int*)w;                                    // reuse cbh (dead after argmin)
    int* hist = (int*)(w + (1u << 20));                          // reuse cbl
    float* lossPart = (float*)(w + (1u << 20) + 4096);           // reuse cbl+4KB

    k_split<<<512, 256, 0, stream>>>(cb, cbh, cbl);
    k_cnorm<<<NB_CODE, 64, 0, stream>>>(cb, cnorm);
    k_argmin<<<M_ROWS / 128, 512, 0, stream>>>(x, cbh, cbl, cnorm, cand);
    hipMemsetAsync(hist, 0, NB_CODE * sizeof(int), stream);      // cbl dead now
    k_rescore<<<1024, 256, 0, stream>>>(x, cb, cnorm, cand, idx_final);
    k_scatter<<<1024, 256, 0, stream>>>(x, cb, idx_final, dout, lossPart, hist);
    k_finalize<<<1, 256, 0, stream>>>(hist, lossPart, dout);
}

// Round 3
// 355.037 us; speedup vs baseline: 3.8207x; 1.7211x over previous
//
#include <hip/hip_runtime.h>
#include <cstddef>
#include <cstdint>

#define N_BATCH 32
#define WIDTH   512
#define T_DIM   2048
#define NB_CODE 1024
#define M_ROWS  65536
#define OUT_ELEMS 33554432
#define IDX_OFF  OUT_ELEMS
#define LOSS_OFF (OUT_ELEMS + M_ROWS)
#define PERP_OFF (LOSS_OFF + 1)
#define MARGIN   0.75f

typedef __attribute__((ext_vector_type(8))) short vshort8;
typedef __attribute__((ext_vector_type(4))) float vfloat4;

typedef __attribute__((address_space(1))) const uint32_t gu32_t;
typedef __attribute__((address_space(3))) uint32_t lu32_t;
static __device__ __forceinline__ void gload16(const void* g, void* l) {
    __builtin_amdgcn_global_load_lds((gu32_t*)g, (lu32_t*)l, 16, 0, 0);
}

static __device__ __forceinline__ unsigned short f2bf(float f) {
    uint32_t u = __float_as_uint(f);
    uint32_t r = (u + 0x7FFFu + ((u >> 16) & 1u)) >> 16;  // RNE
    return (unsigned short)r;
}

// ---------------- workspace layout (bytes) ----------------
// cbh       : [0, 1MB)             codebook hi bf16 [1024][512]
// cnorm     : [1MB, +4KB)
// cand      : [1MB+4KB, +256KB)    packed i1|i2<<10|i3<<20|flags<<30
// idx_final : [1.5MB, +256KB)
// hist      : [2MB, +4KB)
// lossPart  : [2MB+4KB, +4KB)

__global__ __launch_bounds__(256) void k_split(const float* __restrict__ cb,
                                               unsigned short* __restrict__ h) {
    const int i = blockIdx.x * 256 + threadIdx.x;  // 131072 float4s
    float4 v = ((const float4*)cb)[i];
    ushort4 hh;
    hh.x = f2bf(v.x); hh.y = f2bf(v.y); hh.z = f2bf(v.z); hh.w = f2bf(v.w);
    ((ushort4*)h)[i] = hh;
}

__global__ void k_cnorm(const float* __restrict__ cb, float* __restrict__ cnorm) {
    const int c = blockIdx.x;
    const int lane = threadIdx.x;
    const float4* p = (const float4*)(cb + (size_t)c * WIDTH);
    float s = 0.f;
#pragma unroll
    for (int i = 0; i < 2; ++i) {
        float4 v = p[lane + i * 64];
        s += v.x * v.x + v.y * v.y + v.z * v.z + v.w * v.w;
    }
#pragma unroll
    for (int off = 32; off >= 1; off >>= 1) s += __shfl_xor(s, off, 64);
    if (lane == 0) cnorm[c] = s;
}

// hh-screen argmin: 256 thr = 4 waves, 64 rows/block, top-3/row + margin flags.
// LDS tiles [128 codes][64 k] bf16, XOR-swizzled (16B granule), double-buffered,
// filled by global_load_lds with pre-swizzled per-lane global source.
__global__ __launch_bounds__(256, 3) void k_argmin(
    const float* __restrict__ x, const unsigned short* __restrict__ cbh,
    const float* __restrict__ cnorm, uint32_t* __restrict__ cand) {
    __shared__ __align__(16) short lds[2][8192];   // 2 x 16KB
    __shared__ __align__(16) float cns[NB_CODE];

    const int tid = threadIdx.x;
    const int w = tid >> 6, l = tid & 63;
    const int l15 = l & 15, lg = l >> 4;

    // per-lane source swizzle for global_load_lds (linear LDS dest)
    const int rowl = l >> 3;                              // row within 8-row chunk
    const int srccol = ((l & 7) * 16) ^ (rowl << 4);      // bytes within 128B span

#define STAGE(CC, KC, BUF) do {                                                     \
    const char* gb_ = ((const char*)cbh) +                                          \
        (((size_t)((CC) * 128 + w * 32 + rowl)) << 10) + (KC) * 128 + srccol;       \
    short* lb_ = &lds[BUF][w * 2048];                                               \
    gload16(gb_,         lb_);                                                      \
    gload16(gb_ + 8192,  lb_ + 512);                                                \
    gload16(gb_ + 16384, lb_ + 1024);                                               \
    gload16(gb_ + 24576, lb_ + 1536);                                               \
} while (0)

    STAGE(0, 0, 0);  // tile 0 in flight

    for (int i = tid; i < NB_CODE; i += 256) cns[i] = cnorm[i];

    // x fragments: 16 rows/wave, full K=512, bf16 hi only (B-frag: n=l15, k=lg*8+e)
    const int m0w = blockIdx.x * 64 + w * 16;
    const int n = m0w >> 11;
    const int t = (m0w & 2047) + l15;
    const float* xb = x + (size_t)n * WIDTH * T_DIM + t;
    vshort8 xh[16];
#pragma unroll
    for (int ks = 0; ks < 16; ++ks) {
        const int kb = ks * 32 + lg * 8;
#pragma unroll
        for (int e = 0; e < 8; ++e)
            xh[ks][e] = (short)f2bf(xb[(size_t)(kb + e) * T_DIM]);
    }

    // swizzled ds_read bases (shorts): row=fm*16+l15, col=ks2*32+lg*8
    const int mask = (l15 & 7) << 3;
    const int rd0 = l15 * 64 + ((lg * 8) ^ mask);
    const int rd1 = rd0 ^ 32;

    float b1 = 3.4e38f, b2 = 3.4e38f, b3 = 3.4e38f;
    int i1 = 0, i2 = 0, i3 = 0;

    __syncthreads();  // drains gload_lds tile0; cns + (implicitly) x regs ready

    for (int cc = 0; cc < 8; ++cc) {
        vfloat4 acc[8];
#pragma unroll
        for (int fm = 0; fm < 8; ++fm) { vfloat4 z = {0.f, 0.f, 0.f, 0.f}; acc[fm] = z; }

#pragma unroll
        for (int kc = 0; kc < 8; ++kc) {
            const int buf = kc & 1;
            if (cc < 7 || kc < 7) {
                const int cc1 = (kc == 7) ? cc + 1 : cc;
                const int kc1 = (kc == 7) ? 0 : kc + 1;
                if (buf) STAGE(cc1, kc1, 0); else STAGE(cc1, kc1, 1);
            }
            __builtin_amdgcn_s_setprio(1);
#pragma unroll
            for (int fm = 0; fm < 8; ++fm) {
                vshort8 a0 = *(const vshort8*)&lds[buf][rd0 + fm * 1024];
                acc[fm] = __builtin_amdgcn_mfma_f32_16x16x32_bf16(a0, xh[kc * 2], acc[fm], 0, 0, 0);
            }
#pragma unroll
            for (int fm = 0; fm < 8; ++fm) {
                vshort8 a1 = *(const vshort8*)&lds[buf][rd1 + fm * 1024];
                acc[fm] = __builtin_amdgcn_mfma_f32_16x16x32_bf16(a1, xh[kc * 2 + 1], acc[fm], 0, 0, 0);
            }
            __builtin_amdgcn_s_setprio(0);
            if (kc == 7) {
                // score chunk cc: lane covers codes cc*128+fm*16+lg*4+r, row l15
#pragma unroll
                for (int fm = 0; fm < 8; ++fm) {
                    const int cb0 = cc * 128 + fm * 16 + lg * 4;
                    vfloat4 cn = *(const vfloat4*)&cns[cb0];
#pragma unroll
                    for (int r = 0; r < 4; ++r) {
                        const float s = fmaf(-2.f, acc[fm][r], cn[r]);
                        const int c = cb0 + r;
                        const bool lt1 = s < b1, lt2 = s < b2, lt3 = s < b3;
                        b3 = lt3 ? (lt2 ? b2 : s) : b3;  i3 = lt3 ? (lt2 ? i2 : c) : i3;
                        b2 = lt2 ? (lt1 ? b1 : s) : b2;  i2 = lt2 ? (lt1 ? i1 : c) : i2;
                        b1 = lt1 ? s : b1;               i1 = lt1 ? c : i1;
                    }
                }
            }
            if (cc < 7 || kc < 7) __syncthreads();
        }
    }

    // merge top-3 across the 4 lg groups (lane bits 4,5)
#pragma unroll
    for (int off = 16; off <= 32; off <<= 1) {
        const float ob1 = __shfl_xor(b1, off, 64), ob2 = __shfl_xor(b2, off, 64), ob3 = __shfl_xor(b3, off, 64);
        const int oi1 = __shfl_xor(i1, off, 64), oi2 = __shfl_xor(i2, off, 64), oi3 = __shfl_xor(i3, off, 64);
#define INS(S, C) do {                                                        \
        const bool lt1 = (S) < b1, lt2 = (S) < b2, lt3 = (S) < b3;            \
        b3 = lt3 ? (lt2 ? b2 : (S)) : b3;  i3 = lt3 ? (lt2 ? i2 : (C)) : i3; \
        b2 = lt2 ? (lt1 ? b1 : (S)) : b2;  i2 = lt2 ? (lt1 ? i1 : (C)) : i2; \
        b1 = lt1 ? (S) : b1;               i1 = lt1 ? (C) : i1;              \
    } while (0)
        INS(ob1, oi1); INS(ob2, oi2); INS(ob3, oi3);
    }
    if (l < 16) {
        const uint32_t f2 = (b2 - b1 < MARGIN) ? 1u : 0u;
        const uint32_t f3 = (b3 - b1 < MARGIN) ? 1u : 0u;
        cand[m0w + l] = (uint32_t)i1 | ((uint32_t)i2 << 10) | ((uint32_t)i3 << 20) | (f2 << 30) | (f3 << 31);
    }
}

// Exact fp32 rescore of flagged rows (up to 3 candidates); writes final idx.
__global__ __launch_bounds__(256) void k_rescore(
    const float* __restrict__ x, const float* __restrict__ cb,
    const float* __restrict__ cnorm, const uint32_t* __restrict__ cand,
    int* __restrict__ idx_final) {
    __shared__ float pd[3][4][64];
    const int tid = threadIdx.x;
    const int b = blockIdx.x;
    const int n = b >> 5, t0 = (b & 31) * 64;
    const int tl = tid & 63, kq = tid >> 6;
    const int row = n * T_DIM + t0 + tl;
    const uint32_t wv = cand[row];
    const int j1 = (int)(wv & 1023u), j2 = (int)((wv >> 10) & 1023u), j3 = (int)((wv >> 20) & 1023u);
    const bool nd2 = (wv >> 30) & 1u, nd3 = (wv >> 31) & 1u;
    float d1 = 0.f, d2 = 0.f, d3 = 0.f;
    if (nd2) {
        const float* xc = x + (size_t)n * WIDTH * T_DIM + t0 + tl;
        const float* c1 = cb + (size_t)j1 * WIDTH;
        const float* c2 = cb + (size_t)j2 * WIDTH;
        const float* c3 = cb + (size_t)j3 * WIDTH;
#pragma unroll 4
        for (int k = kq * 128; k < kq * 128 + 128; ++k) {
            const float v = xc[(size_t)k * T_DIM];
            d1 = fmaf(v, c1[k], d1);
            d2 = fmaf(v, c2[k], d2);
            if (nd3) d3 = fmaf(v, c3[k], d3);
        }
    }
    pd[0][kq][tl] = d1; pd[1][kq][tl] = d2; pd[2][kq][tl] = d3;
    __syncthreads();
    if (tid < 64) {
        int win = j1;
        if (nd2) {
            float qw = cnorm[j1] - 2.f * (pd[0][0][tid] + pd[0][1][tid] + pd[0][2][tid] + pd[0][3][tid]);
            const float q2 = cnorm[j2] - 2.f * (pd[1][0][tid] + pd[1][1][tid] + pd[1][2][tid] + pd[1][3][tid]);
            if (q2 < qw || (q2 == qw && j2 < win)) { win = j2; qw = q2; }
            if (nd3) {
                const float q3 = cnorm[j3] - 2.f * (pd[2][0][tid] + pd[2][1][tid] + pd[2][2][tid] + pd[2][3][tid]);
                if (q3 < qw || (q3 == qw && j3 < win)) { win = j3; qw = q3; }
            }
        }
        idx_final[row] = win;
    }
}

// Gather codebook[idx] -> out [N][W][T], idx as float, loss partials, histogram.
__global__ __launch_bounds__(256) void k_scatter(
    const float* __restrict__ x, const float* __restrict__ cb,
    const int* __restrict__ idx, float* __restrict__ dout,
    float* __restrict__ lossPart, int* __restrict__ hist) {
    __shared__ int sidx[64];
    __shared__ float swsum[4];
    const int tid = threadIdx.x;
    const int b = blockIdx.x;
    const int n = b >> 5;
    const int t0 = (b & 31) * 64;
    if (tid < 64) {
        const int m = n * T_DIM + t0 + tid;
        const int ii = idx[m];
        sidx[tid] = ii;
        dout[IDX_OFF + m] = (float)ii;
        atomicAdd(&hist[ii], 1);
    }
    __syncthreads();
    const int i = tid & 63;
    const int wq = tid >> 6;
    const int ii = sidx[i];
    float ls = 0.f;
    for (int ww = wq; ww < WIDTH; ww += 4) {
        const float val = cb[(size_t)ii * WIDTH + ww];
        const size_t o = ((size_t)n * WIDTH + ww) * T_DIM + t0 + i;
        dout[o] = val;
        const float d = x[o] - val;
        ls = fmaf(d, d, ls);
    }
#pragma unroll
    for (int off = 32; off >= 1; off >>= 1) ls += __shfl_xor(ls, off, 64);
    if ((tid & 63) == 0) swsum[tid >> 6] = ls;
    __syncthreads();
    if (tid == 0) lossPart[b] = swsum[0] + swsum[1] + swsum[2] + swsum[3];
}

__global__ __launch_bounds__(256) void k_finalize(
    const int* __restrict__ hist, const float* __restrict__ lossPart,
    float* __restrict__ dout) {
    const int tid = threadIdx.x;
    float e = 0.f, ls = 0.f;
    for (int c = tid; c < NB_CODE; c += 256) {
        const float p = (float)hist[c] * (1.0f / (float)M_ROWS);
        e += p * logf(p + 1e-7f);
        ls += lossPart[c];
    }
#pragma unroll
    for (int off = 32; off >= 1; off >>= 1) {
        e += __shfl_xor(e, off, 64);
        ls += __shfl_xor(ls, off, 64);
    }
    __shared__ float se[4], sl[4];
    if ((tid & 63) == 0) { se[tid >> 6] = e; sl[tid >> 6] = ls; }
    __syncthreads();
    if (tid == 0) {
        const float E = se[0] + se[1] + se[2] + se[3];
        const float L = sl[0] + sl[1] + sl[2] + sl[3];
        dout[LOSS_OFF] = L / (float)OUT_ELEMS;
        dout[PERP_OFF] = expf(-E);
    }
}

extern "C" void kernel_launch(void* const* d_in, const int* in_sizes, int n_in,
                              void* d_out, int out_size, void* d_ws, size_t ws_size,
                              hipStream_t stream) {
    const float* x = (const float*)d_in[0];
    const float* cb = (const float*)d_in[1];
    float* dout = (float*)d_out;
    uint8_t* w = (uint8_t*)d_ws;

    unsigned short* cbh = (unsigned short*)w;                       // 1 MB
    float* cnorm = (float*)(w + (1u << 20));                        // 4 KB
    uint32_t* cand = (uint32_t*)(w + (1u << 20) + 4096);            // 256 KB
    int* idx_final = (int*)(w + (1u << 20) + (1u << 19));           // 256 KB @1.5MB
    int* hist = (int*)(w + (2u << 20));                             // 4 KB
    float* lossPart = (float*)(w + (2u << 20) + 4096);              // 4 KB

    hipMemsetAsync(hist, 0, NB_CODE * sizeof(int), stream);
    k_split<<<512, 256, 0, stream>>>(cb, cbh);
    k_cnorm<<<NB_CODE, 64, 0, stream>>>(cb, cnorm);
    k_argmin<<<M_ROWS / 64, 256, 0, stream>>>(x, cbh, cnorm, cand);
    k_rescore<<<1024, 256, 0, stream>>>(x, cb, cnorm, cand, idx_final);
    k_scatter<<<1024, 256, 0, stream>>>(x, cb, idx_final, dout, lossPart, hist);
    k_finalize<<<1, 256, 0, stream>>>(hist, lossPart, dout);
}

// Round 4
// 284.455 us; speedup vs baseline: 4.7687x; 1.2481x over previous
//
#include <hip/hip_runtime.h>
#include <cstddef>
#include <cstdint>

#define N_BATCH 32
#define WIDTH   512
#define T_DIM   2048
#define NB_CODE 1024
#define M_ROWS  65536
#define OUT_ELEMS 33554432
#define IDX_OFF  OUT_ELEMS
#define LOSS_OFF (OUT_ELEMS + M_ROWS)
#define PERP_OFF (LOSS_OFF + 1)
#define MARGIN   0.75f

typedef __attribute__((ext_vector_type(8))) short vshort8;
typedef __attribute__((ext_vector_type(4))) float vfloat4;

typedef __attribute__((address_space(1))) const uint32_t gu32_t;
typedef __attribute__((address_space(3))) uint32_t lu32_t;
static __device__ __forceinline__ void gload16(const void* g, void* l) {
    __builtin_amdgcn_global_load_lds((gu32_t*)g, (lu32_t*)l, 16, 0, 0);
}

static __device__ __forceinline__ unsigned short f2bf(float f) {
    uint32_t u = __float_as_uint(f);
    uint32_t r = (u + 0x7FFFu + ((u >> 16) & 1u)) >> 16;  // RNE
    return (unsigned short)r;
}

// ---------------- workspace layout (bytes) ----------------
// cbh       : [0, 1MB)             codebook hi bf16 [1024][512]
// cnorm     : [1MB, +4KB)
// cand      : [1MB+4KB, +256KB)    packed i1|i2<<10|i3<<20|flags<<30
// idx_final : [1.5MB, +256KB)
// hist      : [2MB, +4KB)
// lossPart  : [2MB+4KB, +4KB)

// Fused: bf16-split codebook + per-code norms + hist zeroing.
__global__ __launch_bounds__(128) void k_prep(const float* __restrict__ cb,
                                              unsigned short* __restrict__ cbh,
                                              float* __restrict__ cnorm,
                                              int* __restrict__ hist) {
    const int c = blockIdx.x, tid = threadIdx.x;
    float4 v = ((const float4*)(cb + (size_t)c * WIDTH))[tid];
    ushort4 h;
    h.x = f2bf(v.x); h.y = f2bf(v.y); h.z = f2bf(v.z); h.w = f2bf(v.w);
    ((ushort4*)(cbh + (size_t)c * WIDTH))[tid] = h;
    float s = v.x * v.x + v.y * v.y + v.z * v.z + v.w * v.w;
#pragma unroll
    for (int off = 32; off >= 1; off >>= 1) s += __shfl_xor(s, off, 64);
    __shared__ float sw[2];
    if ((tid & 63) == 0) sw[tid >> 6] = s;
    __syncthreads();
    if (tid == 0) { cnorm[c] = sw[0] + sw[1]; hist[c] = 0; }
}

// hh-screen argmin: 256 thr = 4 waves, 128 rows/block (32 rows/wave),
// top-3/row + margin flags. LDS codebook tiles [128 codes][64 k] bf16,
// XOR-swizzled, double-buffered, filled by global_load_lds with
// pre-swizzled per-lane global source. Each A-frag ds_read feeds 2 MFMAs.
__global__ __launch_bounds__(256, 2) void k_argmin(
    const float* __restrict__ x, const unsigned short* __restrict__ cbh,
    const float* __restrict__ cnorm, uint32_t* __restrict__ cand) {
    __shared__ __align__(16) short lds[2][8192];   // 2 x 16KB
    __shared__ __align__(16) float cns[NB_CODE];

    const int tid = threadIdx.x;
    const int w = tid >> 6, l = tid & 63;
    const int l15 = l & 15, lg = l >> 4;

    const int rowl = l >> 3;
    const int srccol = ((l & 7) * 16) ^ (rowl << 4);

#define STAGE(CC, KC, BUF) do {                                                     \
    const char* gb_ = ((const char*)cbh) +                                          \
        (((size_t)((CC) * 128 + w * 32 + rowl)) << 10) + (KC) * 128 + srccol;       \
    short* lb_ = &lds[BUF][w * 2048];                                               \
    gload16(gb_,         lb_);                                                      \
    gload16(gb_ + 8192,  lb_ + 512);                                                \
    gload16(gb_ + 16384, lb_ + 1024);                                               \
    gload16(gb_ + 24576, lb_ + 1536);                                               \
} while (0)

    STAGE(0, 0, 0);  // tile 0 in flight

    for (int i = tid; i < NB_CODE; i += 256) cns[i] = cnorm[i];

    // x fragments: 32 rows/wave (two 16-row sets), full K=512, bf16 hi.
    const int m0w = blockIdx.x * 128 + w * 32;
    const int n = m0w >> 11;
    const int t = (m0w & 2047) + l15;
    const float* xb0 = x + (size_t)n * WIDTH * T_DIM + t;
    const float* xb1 = xb0 + 16;
    vshort8 xh0[16], xh1[16];
#pragma unroll
    for (int ks = 0; ks < 16; ++ks) {
        const int kb = ks * 32 + lg * 8;
#pragma unroll
        for (int e = 0; e < 8; ++e) {
            xh0[ks][e] = (short)f2bf(xb0[(size_t)(kb + e) * T_DIM]);
            xh1[ks][e] = (short)f2bf(xb1[(size_t)(kb + e) * T_DIM]);
        }
    }

    // swizzled ds_read bases (shorts): row=fm*16+l15, col=ks2*32+lg*8
    const int mask = (l15 & 7) << 3;
    const int rd0 = l15 * 64 + ((lg * 8) ^ mask);
    const int rd1 = rd0 ^ 32;

    float b1a = 3.4e38f, b2a = 3.4e38f, b3a = 3.4e38f;
    float b1b = 3.4e38f, b2b = 3.4e38f, b3b = 3.4e38f;
    int i1a = 0, i2a = 0, i3a = 0, i1b = 0, i2b = 0, i3b = 0;

#define INS3(B1, B2, B3, I1, I2, I3, S, C) do {                               \
        const bool lt1 = (S) < B1, lt2 = (S) < B2, lt3 = (S) < B3;            \
        B3 = lt3 ? (lt2 ? B2 : (S)) : B3;  I3 = lt3 ? (lt2 ? I2 : (C)) : I3; \
        B2 = lt2 ? (lt1 ? B1 : (S)) : B2;  I2 = lt2 ? (lt1 ? I1 : (C)) : I2; \
        B1 = lt1 ? (S) : B1;               I1 = lt1 ? (C) : I1;              \
    } while (0)

    __syncthreads();  // drains gload_lds tile0

    for (int cc = 0; cc < 8; ++cc) {
        vfloat4 acc0[8], acc1[8];
#pragma unroll
        for (int fm = 0; fm < 8; ++fm) {
            vfloat4 z = {0.f, 0.f, 0.f, 0.f};
            acc0[fm] = z; acc1[fm] = z;
        }

#pragma unroll
        for (int kc = 0; kc < 8; ++kc) {
            const int buf = kc & 1;
            if (cc < 7 || kc < 7) {
                const int cc1 = (kc == 7) ? cc + 1 : cc;
                const int kc1 = (kc == 7) ? 0 : kc + 1;
                if (buf) STAGE(cc1, kc1, 0); else STAGE(cc1, kc1, 1);
            }
            __builtin_amdgcn_s_setprio(1);
#pragma unroll
            for (int fm = 0; fm < 8; ++fm) {
                vshort8 a0 = *(const vshort8*)&lds[buf][rd0 + fm * 1024];
                acc0[fm] = __builtin_amdgcn_mfma_f32_16x16x32_bf16(a0, xh0[kc * 2], acc0[fm], 0, 0, 0);
                acc1[fm] = __builtin_amdgcn_mfma_f32_16x16x32_bf16(a0, xh1[kc * 2], acc1[fm], 0, 0, 0);
            }
#pragma unroll
            for (int fm = 0; fm < 8; ++fm) {
                vshort8 a1 = *(const vshort8*)&lds[buf][rd1 + fm * 1024];
                acc0[fm] = __builtin_amdgcn_mfma_f32_16x16x32_bf16(a1, xh0[kc * 2 + 1], acc0[fm], 0, 0, 0);
                acc1[fm] = __builtin_amdgcn_mfma_f32_16x16x32_bf16(a1, xh1[kc * 2 + 1], acc1[fm], 0, 0, 0);
            }
            __builtin_amdgcn_s_setprio(0);
            if (kc == 7) {
#pragma unroll
                for (int fm = 0; fm < 8; ++fm) {
                    const int cb0 = cc * 128 + fm * 16 + lg * 4;
                    vfloat4 cn = *(const vfloat4*)&cns[cb0];
#pragma unroll
                    for (int r = 0; r < 4; ++r) {
                        const int c = cb0 + r;
                        const float s0 = fmaf(-2.f, acc0[fm][r], cn[r]);
                        INS3(b1a, b2a, b3a, i1a, i2a, i3a, s0, c);
                        const float s1 = fmaf(-2.f, acc1[fm][r], cn[r]);
                        INS3(b1b, b2b, b3b, i1b, i2b, i3b, s1, c);
                    }
                }
            }
            if (cc < 7 || kc < 7) __syncthreads();
        }
    }

    // merge top-3 across the 4 lg groups (lane bits 4,5)
#pragma unroll
    for (int off = 16; off <= 32; off <<= 1) {
        float ob1 = __shfl_xor(b1a, off, 64), ob2 = __shfl_xor(b2a, off, 64), ob3 = __shfl_xor(b3a, off, 64);
        int oi1 = __shfl_xor(i1a, off, 64), oi2 = __shfl_xor(i2a, off, 64), oi3 = __shfl_xor(i3a, off, 64);
        INS3(b1a, b2a, b3a, i1a, i2a, i3a, ob1, oi1);
        INS3(b1a, b2a, b3a, i1a, i2a, i3a, ob2, oi2);
        INS3(b1a, b2a, b3a, i1a, i2a, i3a, ob3, oi3);
        ob1 = __shfl_xor(b1b, off, 64); ob2 = __shfl_xor(b2b, off, 64); ob3 = __shfl_xor(b3b, off, 64);
        oi1 = __shfl_xor(i1b, off, 64); oi2 = __shfl_xor(i2b, off, 64); oi3 = __shfl_xor(i3b, off, 64);
        INS3(b1b, b2b, b3b, i1b, i2b, i3b, ob1, oi1);
        INS3(b1b, b2b, b3b, i1b, i2b, i3b, ob2, oi2);
        INS3(b1b, b2b, b3b, i1b, i2b, i3b, ob3, oi3);
    }
    if (l < 16) {
        uint32_t f2 = (b2a - b1a < MARGIN) ? 1u : 0u;
        uint32_t f3 = (b3a - b1a < MARGIN) ? 1u : 0u;
        cand[m0w + l] = (uint32_t)i1a | ((uint32_t)i2a << 10) | ((uint32_t)i3a << 20) | (f2 << 30) | (f3 << 31);
        f2 = (b2b - b1b < MARGIN) ? 1u : 0u;
        f3 = (b3b - b1b < MARGIN) ? 1u : 0u;
        cand[m0w + 16 + l] = (uint32_t)i1b | ((uint32_t)i2b << 10) | ((uint32_t)i3b << 20) | (f2 << 30) | (f3 << 31);
    }
}

// Exact fp32 rescore of flagged rows (up to 3 candidates); writes final idx.
__global__ __launch_bounds__(256) void k_rescore(
    const float* __restrict__ x, const float* __restrict__ cb,
    const float* __restrict__ cnorm, const uint32_t* __restrict__ cand,
    int* __restrict__ idx_final) {
    __shared__ float pd[3][4][64];
    const int tid = threadIdx.x;
    const int b = blockIdx.x;
    const int n = b >> 5, t0 = (b & 31) * 64;
    const int tl = tid & 63, kq = tid >> 6;
    const int row = n * T_DIM + t0 + tl;
    const uint32_t wv = cand[row];
    const int j1 = (int)(wv & 1023u), j2 = (int)((wv >> 10) & 1023u), j3 = (int)((wv >> 20) & 1023u);
    const bool nd2 = (wv >> 30) & 1u, nd3 = (wv >> 31) & 1u;
    float d1 = 0.f, d2 = 0.f, d3 = 0.f;
    if (nd2) {
        const float* xc = x + (size_t)n * WIDTH * T_DIM + t0 + tl;
        const float* c1 = cb + (size_t)j1 * WIDTH;
        const float* c2 = cb + (size_t)j2 * WIDTH;
        const float* c3 = cb + (size_t)j3 * WIDTH;
#pragma unroll 4
        for (int k = kq * 128; k < kq * 128 + 128; ++k) {
            const float v = xc[(size_t)k * T_DIM];
            d1 = fmaf(v, c1[k], d1);
            d2 = fmaf(v, c2[k], d2);
            if (nd3) d3 = fmaf(v, c3[k], d3);
        }
    }
    pd[0][kq][tl] = d1; pd[1][kq][tl] = d2; pd[2][kq][tl] = d3;
    __syncthreads();
    if (tid < 64) {
        const uint32_t wv2 = cand[n * T_DIM + t0 + tid];
        const int k1 = (int)(wv2 & 1023u), k2 = (int)((wv2 >> 10) & 1023u), k3 = (int)((wv2 >> 20) & 1023u);
        const bool m2 = (wv2 >> 30) & 1u, m3 = (wv2 >> 31) & 1u;
        int win = k1;
        if (m2) {
            float qw = cnorm[k1] - 2.f * (pd[0][0][tid] + pd[0][1][tid] + pd[0][2][tid] + pd[0][3][tid]);
            const float q2 = cnorm[k2] - 2.f * (pd[1][0][tid] + pd[1][1][tid] + pd[1][2][tid] + pd[1][3][tid]);
            if (q2 < qw || (q2 == qw && k2 < win)) { win = k2; qw = q2; }
            if (m3) {
                const float q3 = cnorm[k3] - 2.f * (pd[2][0][tid] + pd[2][1][tid] + pd[2][2][tid] + pd[2][3][tid]);
                if (q3 < qw || (q3 == qw && k3 < win)) { win = k3; qw = q3; }
            }
        }
        idx_final[n * T_DIM + t0 + tid] = win;
    }
}

// Gather codebook[idx] -> out [N][W][T] via LDS transpose staging (coalesced
// cb reads AND coalesced out writes), idx as float, loss partials, histogram.
__global__ __launch_bounds__(256) void k_scatter(
    const float* __restrict__ x, const float* __restrict__ cb,
    const int* __restrict__ idx, float* __restrict__ dout,
    float* __restrict__ lossPart, int* __restrict__ hist) {
    __shared__ int sidx[64];
    __shared__ float tile[64][130];
    __shared__ float swsum[4];
    const int tid = threadIdx.x;
    const int b = blockIdx.x;
    const int n = b >> 5;
    const int t0 = (b & 31) * 64;
    if (tid < 64) {
        const int m = n * T_DIM + t0 + tid;
        const int ii = idx[m];
        sidx[tid] = ii;
        dout[IDX_OFF + m] = (float)ii;
        atomicAdd(&hist[ii], 1);
    }
    __syncthreads();
    const int w = tid >> 6, l = tid & 63;
    float ls = 0.f;
    for (int wc = 0; wc < 4; ++wc) {
        // stage: wave w loads rows w*16..w*16+15, cols wc*128..+127 (coalesced)
#pragma unroll
        for (int rr = 0; rr < 16; ++rr) {
            const int row = w * 16 + rr;
            const float2 v = *(const float2*)(cb + (size_t)sidx[row] * WIDTH + wc * 128 + l * 2);
            *(float2*)&tile[row][l * 2] = v;
        }
        __syncthreads();
        // write out: lanes = t (coalesced stores), wave handles 32 w's
#pragma unroll 8
        for (int wwi = 0; wwi < 32; ++wwi) {
            const int ww = wc * 128 + w * 32 + wwi;
            const float val = tile[l][w * 32 + wwi];
            const size_t o = ((size_t)n * WIDTH + ww) * T_DIM + t0 + l;
            dout[o] = val;
            const float d = x[o] - val;
            ls = fmaf(d, d, ls);
        }
        __syncthreads();
    }
#pragma unroll
    for (int off = 32; off >= 1; off >>= 1) ls += __shfl_xor(ls, off, 64);
    if ((tid & 63) == 0) swsum[tid >> 6] = ls;
    __syncthreads();
    if (tid == 0) lossPart[b] = swsum[0] + swsum[1] + swsum[2] + swsum[3];
}

__global__ __launch_bounds__(256) void k_finalize(
    const int* __restrict__ hist, const float* __restrict__ lossPart,
    float* __restrict__ dout) {
    const int tid = threadIdx.x;
    float e = 0.f, ls = 0.f;
    for (int c = tid; c < NB_CODE; c += 256) {
        const float p = (float)hist[c] * (1.0f / (float)M_ROWS);
        e += p * logf(p + 1e-7f);
        ls += lossPart[c];
    }
#pragma unroll
    for (int off = 32; off >= 1; off >>= 1) {
        e += __shfl_xor(e, off, 64);
        ls += __shfl_xor(ls, off, 64);
    }
    __shared__ float se[4], sl[4];
    if ((tid & 63) == 0) { se[tid >> 6] = e; sl[tid >> 6] = ls; }
    __syncthreads();
    if (tid == 0) {
        const float E = se[0] + se[1] + se[2] + se[3];
        const float L = sl[0] + sl[1] + sl[2] + sl[3];
        dout[LOSS_OFF] = L / (float)OUT_ELEMS;
        dout[PERP_OFF] = expf(-E);
    }
}

extern "C" void kernel_launch(void* const* d_in, const int* in_sizes, int n_in,
                              void* d_out, int out_size, void* d_ws, size_t ws_size,
                              hipStream_t stream) {
    const float* x = (const float*)d_in[0];
    const float* cb = (const float*)d_in[1];
    float* dout = (float*)d_out;
    uint8_t* w = (uint8_t*)d_ws;

    unsigned short* cbh = (unsigned short*)w;                       // 1 MB
    float* cnorm = (float*)(w + (1u << 20));                        // 4 KB
    uint32_t* cand = (uint32_t*)(w + (1u << 20) + 4096);            // 256 KB
    int* idx_final = (int*)(w + (1u << 20) + (1u << 19));           // 256 KB @1.5MB
    int* hist = (int*)(w + (2u << 20));                             // 4 KB
    float* lossPart = (float*)(w + (2u << 20) + 4096);              // 4 KB

    k_prep<<<NB_CODE, 128, 0, stream>>>(cb, cbh, cnorm, hist);
    k_argmin<<<M_ROWS / 128, 256, 0, stream>>>(x, cbh, cnorm, cand);
    k_rescore<<<1024, 256, 0, stream>>>(x, cb, cnorm, cand, idx_final);
    k_scatter<<<1024, 256, 0, stream>>>(x, cb, idx_final, dout, lossPart, hist);
    k_finalize<<<1, 256, 0, stream>>>(hist, lossPart, dout);
}